// Round 13
// baseline (324.899 us; speedup 1.0000x reference)
//
#include <hip/hip_runtime.h>
#include <hip/hip_bf16.h>

#define LOOK   1024
#define PREDN  256
#define TOT    1280
#define SBLEN  1296       // bf16 series + zero tail (max read elem 1286)
#define DPD    128
#define NK     971        // number of keys (T)
#define RPB    122        // valid q-rows per block (2 blocks/pair)
#define NKT    16         // 16 key-tiles of 64
#define SCALE  0.08838834764831845f  // 1/sqrt(128)

typedef __attribute__((ext_vector_type(8))) short short8;
typedef __attribute__((ext_vector_type(4))) float f32x4;

__device__ __forceinline__ unsigned short f2bu(float x) {
    union { __hip_bfloat16 b; unsigned short u; } v;
    v.b = __float2bfloat16(x);
    return v.u;
}
__device__ __forceinline__ unsigned int pack2(float a, float b) {
    return (unsigned int)f2bu(a) | ((unsigned int)f2bu(b) << 16);
}

// 8 contiguous bf16 from series at element idx0 (any parity): 5 dwords + funnel shift.
__device__ __forceinline__ short8 load_sfrag(const unsigned short* s0, int idx0) {
    const unsigned int* p = (const unsigned int*)s0 + (idx0 >> 1);
    const unsigned int sh = (idx0 & 1) << 4;
    unsigned int w0 = p[0], w1 = p[1], w2 = p[2], w3 = p[3], w4 = p[4];
    union { unsigned int u[4]; short8 s; } v;
    v.u[0] = (unsigned int)((((unsigned long long)w1 << 32) | w0) >> sh);
    v.u[1] = (unsigned int)((((unsigned long long)w2 << 32) | w1) >> sh);
    v.u[2] = (unsigned int)((((unsigned long long)w3 << 32) | w2) >> sh);
    v.u[3] = (unsigned int)((((unsigned long long)w4 << 32) | w3) >> sh);
    return v.s;
}
// 8 bf16 from LDS at 8B-aligned (not 16B) address: two b64 reads.
__device__ __forceinline__ short8 ld_b64x2(const unsigned short* p) {
    union { unsigned long long q[2]; short8 s; } v;
    v.q[0] = *(const unsigned long long*)p;
    v.q[1] = *(const unsigned long long*)(p + 4);
    return v.s;
}

// Fused projection of 64 rows (16 per wave, 4 waves) + pe' + in-reg LN -> s_kb.
__device__ __forceinline__ void proj_tile(
    const unsigned short* s_sb0, const unsigned short* s_wpb,
    const unsigned int* s_gb, unsigned short* s_kb,
    const float* __restrict__ peb,
    int widx, int perow, int rowkb, int quad, int kcol)
{
    short8 bw0 = load_sfrag(s_sb0, widx + 8 * quad);
    short8 bw1 = load_sfrag(s_sb0, widx + 32 + 8 * quad);
    f32x4 pc[8];
    #pragma unroll
    for (int mt = 0; mt < 8; ++mt) pc[mt] = (f32x4){0.f, 0.f, 0.f, 0.f};
    const int k7 = kcol & 7;
    #pragma unroll
    for (int mt = 0; mt < 8; ++mt) {
        int e = 16 * mt + kcol;
        short8 a0 = *(const short8*)&s_wpb[e * 64 + ((quad ^ k7) << 3)];
        short8 a1 = *(const short8*)&s_wpb[e * 64 + (((4 + quad) ^ k7) << 3)];
        pc[mt] = __builtin_amdgcn_mfma_f32_16x16x32_bf16(a0, bw0, pc[mt], 0, 0, 0);
        pc[mt] = __builtin_amdgcn_mfma_f32_16x16x32_bf16(a1, bw1, pc[mt], 0, 0, 0);
    }
    float x[8][4];
    float sm = 0.f, sq = 0.f;
    #pragma unroll
    for (int mt = 0; mt < 8; ++mt) {
        float4 pv = *(const float4*)&peb[perow * 128 + 16 * mt + 4 * quad];
        x[mt][0] = pc[mt][0] + pv.x; x[mt][1] = pc[mt][1] + pv.y;
        x[mt][2] = pc[mt][2] + pv.z; x[mt][3] = pc[mt][3] + pv.w;
        #pragma unroll
        for (int r = 0; r < 4; ++r) { sm += x[mt][r]; sq += x[mt][r] * x[mt][r]; }
    }
    sm += __shfl_xor(sm, 16); sq += __shfl_xor(sq, 16);
    sm += __shfl_xor(sm, 32); sq += __shfl_xor(sq, 32);
    float mean = sm * (1.0f / 128.0f);
    float var  = sq * (1.0f / 128.0f) - mean * mean;
    float rs   = rsqrtf(var + 1e-5f);
    #pragma unroll
    for (int mt = 0; mt < 8; ++mt) {
        uint4 gb = *(const uint4*)&s_gb[16 * mt + 4 * quad];
        unsigned int gw[4] = {gb.x, gb.y, gb.z, gb.w};
        float y[4];
        #pragma unroll
        for (int r = 0; r < 4; ++r) {
            float g = __uint_as_float(gw[r] << 16);
            float b = __uint_as_float(gw[r] & 0xFFFF0000u);
            y[r] = (x[mt][r] - mean) * rs * g + b;
        }
        unsigned long long w = ((unsigned long long)pack2(y[2], y[3]) << 32) | pack2(y[0], y[1]);
        *(unsigned long long*)&s_kb[rowkb * 132 + 16 * mt + 4 * quad] = w;
    }
}

// =====================================================================
// Kernel A: hb-split (grid 1024), diet LDS (45,088 B -> 3 blocks/CU),
// no-max softmax (LN bounds |s|<=11.4), per-wave s_P slot (no barrier).
// =====================================================================
__global__ __launch_bounds__(256, 3)
void attn_kernel(const float* __restrict__ lookback,
                 const float* __restrict__ focal,
                 const float* __restrict__ Wp,
                 const float* __restrict__ peb,
                 const float* __restrict__ lng,
                 const float* __restrict__ lnb,
                 unsigned short* __restrict__ flat_hi,
                 unsigned short* __restrict__ flat_lo)
{
    __shared__ unsigned short s_sb0[SBLEN];     //  2592 B series bf16
    __shared__ unsigned short s_wpb[128 * 64];  // 16384 B Wp^T swizzled
    __shared__ unsigned short s_kb[64 * 132];   // 16896 B LN'd rows
    __shared__ unsigned short s_Pw[4 * 16 * 68];//  8704 B probs (per-wave slots)
    __shared__ unsigned int   s_gb[DPD];        //   512 B

    const int t    = threadIdx.x;
    const int pair = blockIdx.x >> 1;
    const int hb   = blockIdx.x & 1;
    const int lane = t & 63;
    const int wave = t >> 6;
    const int quad = lane >> 4;
    const int kcol = lane & 15;

    // ---------------- init ----------------
    {
        if (t < 256) {
            float4 v = ((const float4*)(lookback + pair * LOOK))[t];
            s_sb0[4 * t]     = f2bu(v.x);
            s_sb0[4 * t + 1] = f2bu(v.y);
            s_sb0[4 * t + 2] = f2bu(v.z);
            s_sb0[4 * t + 3] = f2bu(v.w);
        }
        if (t < 64) {
            float4 v = ((const float4*)(focal + pair * PREDN))[t];
            s_sb0[LOOK + 4 * t]     = f2bu(v.x);
            s_sb0[LOOK + 4 * t + 1] = f2bu(v.y);
            s_sb0[LOOK + 4 * t + 2] = f2bu(v.z);
            s_sb0[LOOK + 4 * t + 3] = f2bu(v.w);
        }
        if (t < SBLEN - TOT) s_sb0[TOT + t] = 0;
        #pragma unroll
        for (int j = 0; j < 32; ++j) {            // Wp[k][e] -> swizzled Wp^T
            int fl = j * 256 + t;
            int k = fl >> 7, e = fl & 127;
            s_wpb[e * 64 + (((k >> 3) ^ (e & 7)) << 3) + (k & 7)] = f2bu(Wp[fl]);
        }
        if (t < DPD)
            s_gb[t] = (unsigned int)f2bu(lng[t]) | ((unsigned int)f2bu(lnb[t]) << 16);
    }
    __syncthreads();

    // ---------------- q: 2 tiles of 64 rows ----------------
    short8 aq[2][4];
    for (int qt = 0; qt < 2; ++qt) {
        proj_tile(s_sb0, s_wpb, s_gb, s_kb, peb,
                  972 + hb * RPB + 64 * qt + 16 * wave + kcol,
                  971 + hb * RPB + 64 * qt + 16 * wave + kcol,   // <= 1220 < 1280
                  16 * wave + kcol, quad, kcol);
        __syncthreads();
        if ((wave >> 1) == qt) {
            #pragma unroll
            for (int ntQ = 0; ntQ < 2; ++ntQ) {
                int g = 2 * (wave & 1) + ntQ;
                #pragma unroll
                for (int kc = 0; kc < 4; ++kc)
                    aq[ntQ][kc] = ld_b64x2(&s_kb[(16 * g + kcol) * 132 + 32 * kc + 8 * quad]);
            }
        }
        __syncthreads();
    }

    float lrow[2] = {0.0f, 0.0f};
    f32x4 o[2][4];
    #pragma unroll
    for (int a = 0; a < 2; ++a)
        #pragma unroll
        for (int b = 0; b < 4; ++b) o[a][b] = (f32x4){0.f, 0.f, 0.f, 0.f};

    unsigned short* slot = &s_Pw[wave * (16 * 68)];

    // ---------------- main loop: 16 tiles of 64 keys ----------------
    for (int tile = 0; tile < NKT; ++tile) {
        const int j0 = tile * 64;

        proj_tile(s_sb0, s_wpb, s_gb, s_kb, peb,
                  j0 + 16 * wave + kcol, j0 + 16 * wave + kcol,
                  16 * wave + kcol, quad, kcol);
        __syncthreads();   // B1: k-tile ready

        // QK^T (S^T): D[key][qrow]
        f32x4 sacc[2][4];
        #pragma unroll
        for (int a = 0; a < 2; ++a)
            #pragma unroll
            for (int b = 0; b < 4; ++b) sacc[a][b] = (f32x4){0.f, 0.f, 0.f, 0.f};
        #pragma unroll
        for (int kc = 0; kc < 4; ++kc) {
            short8 ak[4];
            #pragma unroll
            for (int mtK = 0; mtK < 4; ++mtK)
                ak[mtK] = ld_b64x2(&s_kb[(16 * mtK + kcol) * 132 + 32 * kc + 8 * quad]);
            #pragma unroll
            for (int ntQ = 0; ntQ < 2; ++ntQ)
                #pragma unroll
                for (int mtK = 0; mtK < 4; ++mtK)
                    sacc[ntQ][mtK] = __builtin_amdgcn_mfma_f32_16x16x32_bf16(
                        ak[mtK], aq[ntQ][kc], sacc[ntQ][mtK], 0, 0, 0);
        }

        // preload x fragments (shared by both ntQ)
        short8 xf[4][2];
        #pragma unroll
        for (int ntD = 0; ntD < 4; ++ntD)
            #pragma unroll
            for (int kc2 = 0; kc2 < 2; ++kc2)
                xf[ntD][kc2] = load_sfrag(s_sb0, j0 + 1 + 32 * kc2 + 8 * quad + 16 * ntD + kcol);

        // no-max softmax + per-ntQ PV (wave-local slot; no barrier)
        #pragma unroll
        for (int ntQ = 0; ntQ < 2; ++ntQ) {
            float ss = 0.f;
            unsigned long long pk[4];
            #pragma unroll
            for (int mtK = 0; mtK < 4; ++mtK) {
                float P[4];
                #pragma unroll
                for (int r = 0; r < 4; ++r) {
                    int key = j0 + 16 * mtK + 4 * quad + r;
                    float s = (key < NK) ? fminf(sacc[ntQ][mtK][r] * SCALE, 80.0f) : -80.0f;
                    P[r] = __expf(s);
                    ss += P[r];
                }
                pk[mtK] = ((unsigned long long)pack2(P[2], P[3]) << 32) | pack2(P[0], P[1]);
            }
            ss += __shfl_xor(ss, 16);
            ss += __shfl_xor(ss, 32);
            lrow[ntQ] += ss;
            #pragma unroll
            for (int mtK = 0; mtK < 4; ++mtK)
                *(unsigned long long*)&slot[kcol * 68 + 16 * mtK + 4 * quad] = pk[mtK];
            short8 ap[2];
            #pragma unroll
            for (int kc2 = 0; kc2 < 2; ++kc2)
                ap[kc2] = ld_b64x2(&slot[kcol * 68 + 32 * kc2 + 8 * quad]);
            #pragma unroll
            for (int ntD = 0; ntD < 4; ++ntD)
                #pragma unroll
                for (int kc2 = 0; kc2 < 2; ++kc2)
                    o[ntQ][ntD] = __builtin_amdgcn_mfma_f32_16x16x32_bf16(
                        ap[kc2], xf[ntD][kc2], o[ntQ][ntD], 0, 0, 0);
        }
        __syncthreads();   // B2: s_kb free for next tile
    }

    // ---------------- epilogue: hi/lo bf16 split store ----------------
    float inv[2] = {1.0f / lrow[0], 1.0f / lrow[1]};
    #pragma unroll
    for (int ntQ = 0; ntQ < 2; ++ntQ)
        #pragma unroll
        for (int r = 0; r < 4; ++r) {
            float li = __shfl(inv[ntQ], 20 * quad + r);
            int brow = 32 * wave + 16 * ntQ + 4 * quad + r;
            if (brow < RPB) {
                int base = pair * 15616 + (hb * RPB + brow) * 64 + kcol;
                #pragma unroll
                for (int ntD = 0; ntD < 4; ++ntD) {
                    float v = o[ntQ][ntD][r] * li;
                    unsigned short h = f2bu(v);
                    float vh = __uint_as_float((unsigned int)h << 16);
                    flat_hi[base + 16 * ntD] = h;
                    flat_lo[base + 16 * ntD] = f2bu(v - vh);
                }
            }
        }
}

// =====================================================================
// Kernel P: peb = pe + bp (folded bias), 1280x128.
// =====================================================================
__global__ void peb_kernel(const float* __restrict__ pe,
                           const float* __restrict__ bp,
                           float* __restrict__ peb)
{
    int i = blockIdx.x * 256 + threadIdx.x;   // 163840
    peb[i] = pe[i] + bp[i & 127];
}

// =====================================================================
// Kernel B: mlp1 = flat(512x15616) @ W1(15616x256), bf16 MFMA hi/lo
// 3-pass, inline W1 convert (R11-proven). grid = 256 (4m x 4n x 16 kz).
// =====================================================================
__global__ __launch_bounds__(256, 2)
void mlp1_kernel(const unsigned short* __restrict__ Ah,
                 const unsigned short* __restrict__ Al,
                 const float* __restrict__ W1,
                 float* __restrict__ part)
{
    const int bid = blockIdx.x;
    const int bm = bid & 3, bn = (bid >> 2) & 3, bz = bid >> 4;
    const int m0 = bm * 128, n0 = bn * 64;
    const int t0 = bz * 30 + (bz < 8 ? bz : 8);
    const int nt = (bz < 8) ? 31 : 30;

    __shared__ unsigned short sAh[128 * 40];
    __shared__ unsigned short sAl[128 * 40];
    __shared__ unsigned short sBh[64 * 44];
    __shared__ unsigned short sBl[64 * 44];

    const int t = threadIdx.x;
    const int wv = t >> 6, lane = t & 63;
    const int quad = lane >> 4, kcol = lane & 15;
    const int ar = t >> 1, ac16 = (t & 1) * 16;
    const int bk = t >> 3, bn8 = (t & 7) * 8;

    f32x4 acc[8];
    #pragma unroll
    for (int i = 0; i < 8; ++i) acc[i] = (f32x4){0.f, 0.f, 0.f, 0.f};

    for (int tt = 0; tt < nt; ++tt) {
        const int kc = (t0 + tt) * 32;
        *(uint4*)&sAh[ar * 40 + ac16]     = *(const uint4*)(Ah + (m0 + ar) * 15616 + kc + ac16);
        *(uint4*)&sAh[ar * 40 + ac16 + 8] = *(const uint4*)(Ah + (m0 + ar) * 15616 + kc + ac16 + 8);
        *(uint4*)&sAl[ar * 40 + ac16]     = *(const uint4*)(Al + (m0 + ar) * 15616 + kc + ac16);
        *(uint4*)&sAl[ar * 40 + ac16 + 8] = *(const uint4*)(Al + (m0 + ar) * 15616 + kc + ac16 + 8);
        {
            const float* wp = W1 + (kc + bk) * 256 + n0 + bn8;
            float4 wa = *(const float4*)wp;
            float4 wb = *(const float4*)(wp + 4);
            float vv[8] = {wa.x, wa.y, wa.z, wa.w, wb.x, wb.y, wb.z, wb.w};
            #pragma unroll
            for (int i = 0; i < 8; ++i) {
                unsigned short h = f2bu(vv[i]);
                float vh = __uint_as_float((unsigned int)h << 16);
                sBh[(bn8 + i) * 44 + bk] = h;
                sBl[(bn8 + i) * 44 + bk] = f2bu(vv[i] - vh);
            }
        }
        __syncthreads();
        short8 bh = ld_b64x2(&sBh[(16 * wv + kcol) * 44 + quad * 8]);
        short8 bl = ld_b64x2(&sBl[(16 * wv + kcol) * 44 + quad * 8]);
        #pragma unroll
        for (int mt = 0; mt < 8; ++mt) {
            short8 ah = *(const short8*)&sAh[(16 * mt + kcol) * 40 + quad * 8];
            short8 al = *(const short8*)&sAl[(16 * mt + kcol) * 40 + quad * 8];
            acc[mt] = __builtin_amdgcn_mfma_f32_16x16x32_bf16(ah, bh, acc[mt], 0, 0, 0);
            acc[mt] = __builtin_amdgcn_mfma_f32_16x16x32_bf16(al, bh, acc[mt], 0, 0, 0);
            acc[mt] = __builtin_amdgcn_mfma_f32_16x16x32_bf16(ah, bl, acc[mt], 0, 0, 0);
        }
        __syncthreads();
    }
    float* dst = part + bz * (512 * 256);
    #pragma unroll
    for (int mt = 0; mt < 8; ++mt)
        #pragma unroll
        for (int r = 0; r < 4; ++r)
            dst[(m0 + 16 * mt + 4 * quad + r) * 256 + n0 + 16 * wv + kcol] = acc[mt][r];
}

// =====================================================================
// Kernel C: reduce 16 partials + bias + exact GELU -> H (512x256).
// =====================================================================
__global__ void gelu_kernel(const float* __restrict__ part,
                            const float* __restrict__ b1,
                            float* __restrict__ H)
{
    const int i = blockIdx.x * 256 + threadIdx.x;
    float s = 0.0f;
    #pragma unroll
    for (int ks = 0; ks < 16; ++ks) s += part[ks * 131072 + i];
    s += b1[i & 255];
    H[i] = 0.5f * s * (1.0f + erff(s * 0.7071067811865475f));
}

// =====================================================================
// Kernel D: out = H(512x256) @ W2(256x256) + b2 (fp32 out).
// =====================================================================
__global__ __launch_bounds__(256, 2)
void mlp2_kernel(const float* __restrict__ H,
                 const float* __restrict__ W2,
                 const float* __restrict__ b2,
                 float* __restrict__ out)
{
    const int bm = blockIdx.x & 7, bn = blockIdx.x >> 3;
    const int m0 = bm * 64, n0 = bn * 64;
    __shared__ float sA[64 * 36];
    __shared__ float sB[32 * 68];
    float acc[16];
    #pragma unroll
    for (int i = 0; i < 16; ++i) acc[i] = 0.0f;

    const int wv = threadIdx.x >> 6, ln = threadIdx.x & 63;
    const int tm = 4 * wv + (ln >> 4), tn = ln & 15;
    const int r = threadIdx.x >> 3;
    const int c4 = (threadIdx.x & 7) * 4;
    const int c8 = (threadIdx.x & 7) * 8;

    for (int tt = 0; tt < 8; ++tt) {
        const int kc = tt * 32;
        *(float4*)&sA[r * 36 + c4]        = *(const float4*)(H + (m0 + r) * 256 + kc + c4);
        *(float4*)&sA[(r + 32) * 36 + c4] = *(const float4*)(H + (m0 + r + 32) * 256 + kc + c4);
        *(float4*)&sB[r * 68 + c8]     = *(const float4*)(W2 + (kc + r) * 256 + n0 + c8);
        *(float4*)&sB[r * 68 + c8 + 4] = *(const float4*)(W2 + (kc + r) * 256 + n0 + c8 + 4);
        __syncthreads();
        #pragma unroll
        for (int kg = 0; kg < 8; ++kg) {
            float4 a[4], b[4];
            #pragma unroll
            for (int i = 0; i < 4; ++i) a[i] = *(const float4*)&sA[(4 * tm + i) * 36 + 4 * kg];
            #pragma unroll
            for (int j = 0; j < 4; ++j) b[j] = *(const float4*)&sB[(4 * kg + j) * 68 + 4 * tn];
            #pragma unroll
            for (int i = 0; i < 4; ++i) {
                acc[4*i+0] += a[i].x*b[0].x + a[i].y*b[1].x + a[i].z*b[2].x + a[i].w*b[3].x;
                acc[4*i+1] += a[i].x*b[0].y + a[i].y*b[1].y + a[i].z*b[2].y + a[i].w*b[3].y;
                acc[4*i+2] += a[i].x*b[0].z + a[i].y*b[1].z + a[i].z*b[2].z + a[i].w*b[3].z;
                acc[4*i+3] += a[i].x*b[0].w + a[i].y*b[1].w + a[i].z*b[2].w + a[i].w*b[3].w;
            }
        }
        __syncthreads();
    }
    #pragma unroll
    for (int i = 0; i < 4; ++i)
        #pragma unroll
        for (int j = 0; j < 4; ++j) {
            const int m = m0 + 4 * tm + i, n = n0 + 4 * tn + j;
            out[m * 256 + n] = acc[4 * i + j] + b2[n];
        }
}

extern "C" void kernel_launch(void* const* d_in, const int* in_sizes, int n_in,
                              void* d_out, int out_size, void* d_ws, size_t ws_size,
                              hipStream_t stream) {
    (void)in_sizes; (void)n_in; (void)out_size; (void)ws_size;
    const float* lookback = (const float*)d_in[0];
    const float* focal    = (const float*)d_in[1];
    const float* Wp       = (const float*)d_in[2];
    const float* bp       = (const float*)d_in[3];
    const float* pe       = (const float*)d_in[4];
    const float* lng      = (const float*)d_in[5];
    const float* lnb      = (const float*)d_in[6];
    const float* W1       = (const float*)d_in[7];
    const float* b1       = (const float*)d_in[8];
    const float* W2       = (const float*)d_in[9];
    const float* b2       = (const float*)d_in[10];

    // R11-proven 40.9 MB layout (no big-path / w1cvt — implicated in the
    // R12 post-timing divergence; isolation round).
    unsigned short* flat_hi = (unsigned short*)d_ws;        // 15,990,784 B
    unsigned short* flat_lo = flat_hi + 512 * 15616;        // 15,990,784 B
    float* part = (float*)(flat_lo + 512 * 15616);          //  8,388,608 B
    float* H    = part + 16 * 512 * 256;                    //    524,288 B
    float* peb  = part;   // alias: read by attn before mlp1 writes part

    hipLaunchKernelGGL(peb_kernel, dim3(640), dim3(256), 0, stream, pe, bp, peb);
    hipLaunchKernelGGL(attn_kernel, dim3(1024), dim3(256), 0, stream,
                       lookback, focal, Wp, peb, lng, lnb, flat_hi, flat_lo);
    hipLaunchKernelGGL(mlp1_kernel, dim3(256), dim3(256), 0, stream,
                       flat_hi, flat_lo, W1, part);
    hipLaunchKernelGGL(gelu_kernel, dim3(512), dim3(256), 0, stream, part, b1, H);
    hipLaunchKernelGGL(mlp2_kernel, dim3(32), dim3(256), 0, stream, H, W2, b2,
                       (float*)d_out);
}

// Round 14
// 277.101 us; speedup vs baseline: 1.1725x; 1.1725x over previous
//
#include <hip/hip_runtime.h>
#include <hip/hip_bf16.h>

#define LOOK   1024
#define PREDN  256
#define TOT    1280
#define SBLEN  1296       // bf16 series + zero tail (max read elem 1291)
#define DPD    128
#define NK     971        // number of keys (T)
#define RPBT   244        // valid q-rows per pair (one block per pair)
#define NKT    16         // 16 key-tiles of 64
#define SCALE  0.08838834764831845f  // 1/sqrt(128)

typedef __attribute__((ext_vector_type(8))) short short8;
typedef __attribute__((ext_vector_type(4))) float f32x4;

__device__ __forceinline__ unsigned short f2bu(float x) {
    union { __hip_bfloat16 b; unsigned short u; } v;
    v.b = __float2bfloat16(x);
    return v.u;
}
__device__ __forceinline__ unsigned int pack2(float a, float b) {
    return (unsigned int)f2bu(a) | ((unsigned int)f2bu(b) << 16);
}

// 8 contiguous bf16 from series at element idx0 (any parity): 5 dwords + funnel shift.
__device__ __forceinline__ short8 load_sfrag(const unsigned short* s0, int idx0) {
    const unsigned int* p = (const unsigned int*)s0 + (idx0 >> 1);
    const unsigned int sh = (idx0 & 1) << 4;
    unsigned int w0 = p[0], w1 = p[1], w2 = p[2], w3 = p[3], w4 = p[4];
    union { unsigned int u[4]; short8 s; } v;
    v.u[0] = (unsigned int)((((unsigned long long)w1 << 32) | w0) >> sh);
    v.u[1] = (unsigned int)((((unsigned long long)w2 << 32) | w1) >> sh);
    v.u[2] = (unsigned int)((((unsigned long long)w3 << 32) | w2) >> sh);
    v.u[3] = (unsigned int)((((unsigned long long)w4 << 32) | w3) >> sh);
    return v.s;
}
// 8 bf16 from LDS at 8B-aligned (not 16B) address: two b64 reads.
__device__ __forceinline__ short8 ld_b64x2(const unsigned short* p) {
    union { unsigned long long q[2]; short8 s; } v;
    v.q[0] = *(const unsigned long long*)p;
    v.q[1] = *(const unsigned long long*)(p + 4);
    return v.s;
}

// Fused projection of 64 rows (16 per wave, 4 waves) + pe' + in-reg LN -> s_kb.
__device__ __forceinline__ void proj_tile(
    const unsigned short* s_sb0, const unsigned short* s_wpb,
    const unsigned int* s_gb, unsigned short* s_kb,
    const float* __restrict__ peb,
    int widx, int perow, int rowkb, int quad, int kcol)
{
    short8 bw0 = load_sfrag(s_sb0, widx + 8 * quad);
    short8 bw1 = load_sfrag(s_sb0, widx + 32 + 8 * quad);
    f32x4 pc[8];
    #pragma unroll
    for (int mt = 0; mt < 8; ++mt) pc[mt] = (f32x4){0.f, 0.f, 0.f, 0.f};
    const int k7 = kcol & 7;
    #pragma unroll
    for (int mt = 0; mt < 8; ++mt) {
        int e = 16 * mt + kcol;
        short8 a0 = *(const short8*)&s_wpb[e * 64 + ((quad ^ k7) << 3)];
        short8 a1 = *(const short8*)&s_wpb[e * 64 + (((4 + quad) ^ k7) << 3)];
        pc[mt] = __builtin_amdgcn_mfma_f32_16x16x32_bf16(a0, bw0, pc[mt], 0, 0, 0);
        pc[mt] = __builtin_amdgcn_mfma_f32_16x16x32_bf16(a1, bw1, pc[mt], 0, 0, 0);
    }
    float x[8][4];
    float sm = 0.f, sq = 0.f;
    #pragma unroll
    for (int mt = 0; mt < 8; ++mt) {
        float4 pv = *(const float4*)&peb[perow * 128 + 16 * mt + 4 * quad];
        x[mt][0] = pc[mt][0] + pv.x; x[mt][1] = pc[mt][1] + pv.y;
        x[mt][2] = pc[mt][2] + pv.z; x[mt][3] = pc[mt][3] + pv.w;
        #pragma unroll
        for (int r = 0; r < 4; ++r) { sm += x[mt][r]; sq += x[mt][r] * x[mt][r]; }
    }
    sm += __shfl_xor(sm, 16); sq += __shfl_xor(sq, 16);
    sm += __shfl_xor(sm, 32); sq += __shfl_xor(sq, 32);
    float mean = sm * (1.0f / 128.0f);
    float var  = sq * (1.0f / 128.0f) - mean * mean;
    float rs   = rsqrtf(var + 1e-5f);
    #pragma unroll
    for (int mt = 0; mt < 8; ++mt) {
        uint4 gb = *(const uint4*)&s_gb[16 * mt + 4 * quad];
        unsigned int gw[4] = {gb.x, gb.y, gb.z, gb.w};
        float y[4];
        #pragma unroll
        for (int r = 0; r < 4; ++r) {
            float g = __uint_as_float(gw[r] << 16);
            float b = __uint_as_float(gw[r] & 0xFFFF0000u);
            y[r] = (x[mt][r] - mean) * rs * g + b;
        }
        unsigned long long w = ((unsigned long long)pack2(y[2], y[3]) << 32) | pack2(y[0], y[1]);
        *(unsigned long long*)&s_kb[rowkb * 132 + 16 * mt + 4 * quad] = w;
    }
}

// =====================================================================
// Kernel A: merged-pair (grid 512, R11-proven) + no-max softmax +
// per-wave P slot (R13-proven). Wave w owns q-rows 64w..64w+63.
// LDS = 45,088 B; 2 blocks/CU by grid; k-proj once per pair per tile.
// =====================================================================
__global__ __launch_bounds__(256, 2)
void attn_kernel(const float* __restrict__ lookback,
                 const float* __restrict__ focal,
                 const float* __restrict__ Wp,
                 const float* __restrict__ peb,
                 const float* __restrict__ lng,
                 const float* __restrict__ lnb,
                 unsigned short* __restrict__ flat_hi,
                 unsigned short* __restrict__ flat_lo)
{
    __shared__ unsigned short s_sb0[SBLEN];     //  2592 B series bf16
    __shared__ unsigned short s_wpb[128 * 64];  // 16384 B Wp^T swizzled
    __shared__ unsigned short s_kb[64 * 132];   // 16896 B LN'd rows
    __shared__ unsigned short s_Pw[4 * 16 * 68];//  8704 B probs (per-wave slots)
    __shared__ unsigned int   s_gb[DPD];        //   512 B

    const int t    = threadIdx.x;
    const int pair = blockIdx.x;
    const int lane = t & 63;
    const int wave = t >> 6;
    const int quad = lane >> 4;
    const int kcol = lane & 15;

    // ---------------- init ----------------
    {
        if (t < 256) {
            float4 v = ((const float4*)(lookback + pair * LOOK))[t];
            s_sb0[4 * t]     = f2bu(v.x);
            s_sb0[4 * t + 1] = f2bu(v.y);
            s_sb0[4 * t + 2] = f2bu(v.z);
            s_sb0[4 * t + 3] = f2bu(v.w);
        }
        if (t < 64) {
            float4 v = ((const float4*)(focal + pair * PREDN))[t];
            s_sb0[LOOK + 4 * t]     = f2bu(v.x);
            s_sb0[LOOK + 4 * t + 1] = f2bu(v.y);
            s_sb0[LOOK + 4 * t + 2] = f2bu(v.z);
            s_sb0[LOOK + 4 * t + 3] = f2bu(v.w);
        }
        if (t < SBLEN - TOT) s_sb0[TOT + t] = 0;
        #pragma unroll
        for (int j = 0; j < 32; ++j) {            // Wp[k][e] -> swizzled Wp^T
            int fl = j * 256 + t;
            int k = fl >> 7, e = fl & 127;
            s_wpb[e * 64 + (((k >> 3) ^ (e & 7)) << 3) + (k & 7)] = f2bu(Wp[fl]);
        }
        if (t < DPD)
            s_gb[t] = (unsigned int)f2bu(lng[t]) | ((unsigned int)f2bu(lnb[t]) << 16);
    }
    __syncthreads();

    // ---------------- q: 4 tiles of 64 rows; wave w keeps tile qt==w ----
    short8 aq[4][4];
    for (int qt = 0; qt < 4; ++qt) {
        proj_tile(s_sb0, s_wpb, s_gb, s_kb, peb,
                  972 + 64 * qt + 16 * wave + kcol,
                  971 + 64 * qt + 16 * wave + kcol,   // peb row <= 1226 < 1280
                  16 * wave + kcol, quad, kcol);
        __syncthreads();
        if (wave == qt) {
            #pragma unroll
            for (int ntQ = 0; ntQ < 4; ++ntQ)
                #pragma unroll
                for (int kc = 0; kc < 4; ++kc)
                    aq[ntQ][kc] = ld_b64x2(&s_kb[(16 * ntQ + kcol) * 132 + 32 * kc + 8 * quad]);
        }
        __syncthreads();
    }

    float lrow[4] = {0.0f, 0.0f, 0.0f, 0.0f};
    f32x4 o[4][4];
    #pragma unroll
    for (int a = 0; a < 4; ++a)
        #pragma unroll
        for (int b = 0; b < 4; ++b) o[a][b] = (f32x4){0.f, 0.f, 0.f, 0.f};

    unsigned short* slot = &s_Pw[wave * (16 * 68)];

    // ---------------- main loop: 16 tiles of 64 keys ----------------
    for (int tile = 0; tile < NKT; ++tile) {
        const int j0 = tile * 64;

        proj_tile(s_sb0, s_wpb, s_gb, s_kb, peb,
                  j0 + 16 * wave + kcol, j0 + 16 * wave + kcol,
                  16 * wave + kcol, quad, kcol);
        __syncthreads();   // B1: k-tile ready

        // QK^T (S^T): D[key][qrow]; A = k rows (shared), B = aq
        f32x4 sacc[4][4];
        #pragma unroll
        for (int a = 0; a < 4; ++a)
            #pragma unroll
            for (int b = 0; b < 4; ++b) sacc[a][b] = (f32x4){0.f, 0.f, 0.f, 0.f};
        #pragma unroll
        for (int kc = 0; kc < 4; ++kc) {
            short8 ak[4];
            #pragma unroll
            for (int mtK = 0; mtK < 4; ++mtK)
                ak[mtK] = ld_b64x2(&s_kb[(16 * mtK + kcol) * 132 + 32 * kc + 8 * quad]);
            #pragma unroll
            for (int ntQ = 0; ntQ < 4; ++ntQ)
                #pragma unroll
                for (int mtK = 0; mtK < 4; ++mtK)
                    sacc[ntQ][mtK] = __builtin_amdgcn_mfma_f32_16x16x32_bf16(
                        ak[mtK], aq[ntQ][kc], sacc[ntQ][mtK], 0, 0, 0);
        }

        // preload x fragments (shared by all ntQ)
        short8 xf[4][2];
        #pragma unroll
        for (int ntD = 0; ntD < 4; ++ntD)
            #pragma unroll
            for (int kc2 = 0; kc2 < 2; ++kc2)
                xf[ntD][kc2] = load_sfrag(s_sb0, j0 + 1 + 32 * kc2 + 8 * quad + 16 * ntD + kcol);

        // no-max softmax + per-ntQ PV (wave-local slot; no barrier)
        #pragma unroll
        for (int ntQ = 0; ntQ < 4; ++ntQ) {
            float ss = 0.f;
            unsigned long long pk[4];
            #pragma unroll
            for (int mtK = 0; mtK < 4; ++mtK) {
                float P[4];
                #pragma unroll
                for (int r = 0; r < 4; ++r) {
                    int key = j0 + 16 * mtK + 4 * quad + r;
                    float s = (key < NK) ? fminf(sacc[ntQ][mtK][r] * SCALE, 80.0f) : -80.0f;
                    P[r] = __expf(s);
                    ss += P[r];
                }
                pk[mtK] = ((unsigned long long)pack2(P[2], P[3]) << 32) | pack2(P[0], P[1]);
            }
            ss += __shfl_xor(ss, 16);
            ss += __shfl_xor(ss, 32);
            lrow[ntQ] += ss;
            #pragma unroll
            for (int mtK = 0; mtK < 4; ++mtK)
                *(unsigned long long*)&slot[kcol * 68 + 16 * mtK + 4 * quad] = pk[mtK];
            short8 ap[2];
            #pragma unroll
            for (int kc2 = 0; kc2 < 2; ++kc2)
                ap[kc2] = ld_b64x2(&slot[kcol * 68 + 32 * kc2 + 8 * quad]);
            #pragma unroll
            for (int ntD = 0; ntD < 4; ++ntD)
                #pragma unroll
                for (int kc2 = 0; kc2 < 2; ++kc2)
                    o[ntQ][ntD] = __builtin_amdgcn_mfma_f32_16x16x32_bf16(
                        ap[kc2], xf[ntD][kc2], o[ntQ][ntD], 0, 0, 0);
        }
        __syncthreads();   // B2: s_kb free for next tile
    }

    // ---------------- epilogue: hi/lo bf16 split store ----------------
    float inv[4] = {1.0f / lrow[0], 1.0f / lrow[1], 1.0f / lrow[2], 1.0f / lrow[3]};
    #pragma unroll
    for (int ntQ = 0; ntQ < 4; ++ntQ)
        #pragma unroll
        for (int r = 0; r < 4; ++r) {
            float li = __shfl(inv[ntQ], 20 * quad + r);
            int brow = 64 * wave + 16 * ntQ + 4 * quad + r;
            if (brow < RPBT) {
                int base = pair * 15616 + brow * 64 + kcol;
                #pragma unroll
                for (int ntD = 0; ntD < 4; ++ntD) {
                    float v = o[ntQ][ntD][r] * li;
                    unsigned short h = f2bu(v);
                    float vh = __uint_as_float((unsigned int)h << 16);
                    flat_hi[base + 16 * ntD] = h;
                    flat_lo[base + 16 * ntD] = f2bu(v - vh);
                }
            }
        }
}

// =====================================================================
// Kernel P: peb = pe + bp (folded bias), 1280x128.
// =====================================================================
__global__ void peb_kernel(const float* __restrict__ pe,
                           const float* __restrict__ bp,
                           float* __restrict__ peb)
{
    int i = blockIdx.x * 256 + threadIdx.x;   // 163840
    peb[i] = pe[i] + bp[i & 127];
}

// =====================================================================
// Kernel B: mlp1 = flat(512x15616) @ W1(15616x256), bf16 MFMA hi/lo
// 3-pass, inline W1 convert. grid = 512 (4m x 4n x 32 k-splits)
// -> 2 blocks/CU.
// =====================================================================
__global__ __launch_bounds__(256, 2)
void mlp1_kernel(const unsigned short* __restrict__ Ah,
                 const unsigned short* __restrict__ Al,
                 const float* __restrict__ W1,
                 float* __restrict__ part)
{
    const int bid = blockIdx.x;
    const int bm = bid & 3, bn = (bid >> 2) & 3, bz = bid >> 4;   // bz 0..31
    const int m0 = bm * 128, n0 = bn * 64;
    const int t0 = bz * 15 + (bz < 8 ? bz : 8);   // 488 = 8*16 + 24*15
    const int nt = (bz < 8) ? 16 : 15;

    __shared__ unsigned short sAh[128 * 40];
    __shared__ unsigned short sAl[128 * 40];
    __shared__ unsigned short sBh[64 * 44];
    __shared__ unsigned short sBl[64 * 44];

    const int t = threadIdx.x;
    const int wv = t >> 6, lane = t & 63;
    const int quad = lane >> 4, kcol = lane & 15;
    const int ar = t >> 1, ac16 = (t & 1) * 16;
    const int bk = t >> 3, bn8 = (t & 7) * 8;

    f32x4 acc[8];
    #pragma unroll
    for (int i = 0; i < 8; ++i) acc[i] = (f32x4){0.f, 0.f, 0.f, 0.f};

    for (int tt = 0; tt < nt; ++tt) {
        const int kc = (t0 + tt) * 32;
        *(uint4*)&sAh[ar * 40 + ac16]     = *(const uint4*)(Ah + (m0 + ar) * 15616 + kc + ac16);
        *(uint4*)&sAh[ar * 40 + ac16 + 8] = *(const uint4*)(Ah + (m0 + ar) * 15616 + kc + ac16 + 8);
        *(uint4*)&sAl[ar * 40 + ac16]     = *(const uint4*)(Al + (m0 + ar) * 15616 + kc + ac16);
        *(uint4*)&sAl[ar * 40 + ac16 + 8] = *(const uint4*)(Al + (m0 + ar) * 15616 + kc + ac16 + 8);
        {
            const float* wp = W1 + (kc + bk) * 256 + n0 + bn8;
            float4 wa = *(const float4*)wp;
            float4 wb = *(const float4*)(wp + 4);
            float vv[8] = {wa.x, wa.y, wa.z, wa.w, wb.x, wb.y, wb.z, wb.w};
            #pragma unroll
            for (int i = 0; i < 8; ++i) {
                unsigned short h = f2bu(vv[i]);
                float vh = __uint_as_float((unsigned int)h << 16);
                sBh[(bn8 + i) * 44 + bk] = h;
                sBl[(bn8 + i) * 44 + bk] = f2bu(vv[i] - vh);
            }
        }
        __syncthreads();
        short8 bh = ld_b64x2(&sBh[(16 * wv + kcol) * 44 + quad * 8]);
        short8 bl = ld_b64x2(&sBl[(16 * wv + kcol) * 44 + quad * 8]);
        #pragma unroll
        for (int mt = 0; mt < 8; ++mt) {
            short8 ah = *(const short8*)&sAh[(16 * mt + kcol) * 40 + quad * 8];
            short8 al = *(const short8*)&sAl[(16 * mt + kcol) * 40 + quad * 8];
            acc[mt] = __builtin_amdgcn_mfma_f32_16x16x32_bf16(ah, bh, acc[mt], 0, 0, 0);
            acc[mt] = __builtin_amdgcn_mfma_f32_16x16x32_bf16(al, bh, acc[mt], 0, 0, 0);
            acc[mt] = __builtin_amdgcn_mfma_f32_16x16x32_bf16(ah, bl, acc[mt], 0, 0, 0);
        }
        __syncthreads();
    }
    float* dst = part + bz * (512 * 256);
    #pragma unroll
    for (int mt = 0; mt < 8; ++mt)
        #pragma unroll
        for (int r = 0; r < 4; ++r)
            dst[(m0 + 16 * mt + 4 * quad + r) * 256 + n0 + 16 * wv + kcol] = acc[mt][r];
}

// =====================================================================
// Kernel C: reduce 32 partials + bias + exact GELU -> H (512x256).
// =====================================================================
__global__ void gelu_kernel(const float* __restrict__ part,
                            const float* __restrict__ b1,
                            float* __restrict__ H)
{
    const int i = blockIdx.x * 256 + threadIdx.x;
    float s = 0.0f;
    #pragma unroll
    for (int ks = 0; ks < 32; ++ks) s += part[ks * 131072 + i];
    s += b1[i & 255];
    H[i] = 0.5f * s * (1.0f + erff(s * 0.7071067811865475f));
}

// =====================================================================
// Kernel D: out = H(512x256) @ W2(256x256) + b2 (fp32 out).
// =====================================================================
__global__ __launch_bounds__(256, 2)
void mlp2_kernel(const float* __restrict__ H,
                 const float* __restrict__ W2,
                 const float* __restrict__ b2,
                 float* __restrict__ out)
{
    const int bm = blockIdx.x & 7, bn = blockIdx.x >> 3;
    const int m0 = bm * 64, n0 = bn * 64;
    __shared__ float sA[64 * 36];
    __shared__ float sB[32 * 68];
    float acc[16];
    #pragma unroll
    for (int i = 0; i < 16; ++i) acc[i] = 0.0f;

    const int wv = threadIdx.x >> 6, ln = threadIdx.x & 63;
    const int tm = 4 * wv + (ln >> 4), tn = ln & 15;
    const int r = threadIdx.x >> 3;
    const int c4 = (threadIdx.x & 7) * 4;
    const int c8 = (threadIdx.x & 7) * 8;

    for (int tt = 0; tt < 8; ++tt) {
        const int kc = tt * 32;
        *(float4*)&sA[r * 36 + c4]        = *(const float4*)(H + (m0 + r) * 256 + kc + c4);
        *(float4*)&sA[(r + 32) * 36 + c4] = *(const float4*)(H + (m0 + r + 32) * 256 + kc + c4);
        *(float4*)&sB[r * 68 + c8]     = *(const float4*)(W2 + (kc + r) * 256 + n0 + c8);
        *(float4*)&sB[r * 68 + c8 + 4] = *(const float4*)(W2 + (kc + r) * 256 + n0 + c8 + 4);
        __syncthreads();
        #pragma unroll
        for (int kg = 0; kg < 8; ++kg) {
            float4 a[4], b[4];
            #pragma unroll
            for (int i = 0; i < 4; ++i) a[i] = *(const float4*)&sA[(4 * tm + i) * 36 + 4 * kg];
            #pragma unroll
            for (int j = 0; j < 4; ++j) b[j] = *(const float4*)&sB[(4 * kg + j) * 68 + 4 * tn];
            #pragma unroll
            for (int i = 0; i < 4; ++i) {
                acc[4*i+0] += a[i].x*b[0].x + a[i].y*b[1].x + a[i].z*b[2].x + a[i].w*b[3].x;
                acc[4*i+1] += a[i].x*b[0].y + a[i].y*b[1].y + a[i].z*b[2].y + a[i].w*b[3].y;
                acc[4*i+2] += a[i].x*b[0].z + a[i].y*b[1].z + a[i].z*b[2].z + a[i].w*b[3].z;
                acc[4*i+3] += a[i].x*b[0].w + a[i].y*b[1].w + a[i].z*b[2].w + a[i].w*b[3].w;
            }
        }
        __syncthreads();
    }
    #pragma unroll
    for (int i = 0; i < 4; ++i)
        #pragma unroll
        for (int j = 0; j < 4; ++j) {
            const int m = m0 + 4 * tm + i, n = n0 + 4 * tn + j;
            out[m * 256 + n] = acc[4 * i + j] + b2[n];
        }
}

extern "C" void kernel_launch(void* const* d_in, const int* in_sizes, int n_in,
                              void* d_out, int out_size, void* d_ws, size_t ws_size,
                              hipStream_t stream) {
    (void)in_sizes; (void)n_in; (void)out_size; (void)ws_size;
    const float* lookback = (const float*)d_in[0];
    const float* focal    = (const float*)d_in[1];
    const float* Wp       = (const float*)d_in[2];
    const float* bp       = (const float*)d_in[3];
    const float* pe       = (const float*)d_in[4];
    const float* lng      = (const float*)d_in[5];
    const float* lnb      = (const float*)d_in[6];
    const float* W1       = (const float*)d_in[7];
    const float* b1       = (const float*)d_in[8];
    const float* W2       = (const float*)d_in[9];
    const float* b2       = (const float*)d_in[10];

    // 49.3 MB layout (ws_size >= 56.9 MB proven by R12's big-path execution).
    unsigned short* flat_hi = (unsigned short*)d_ws;        // 15,990,784 B
    unsigned short* flat_lo = flat_hi + 512 * 15616;        // 15,990,784 B
    float* part = (float*)(flat_lo + 512 * 15616);          // 16,777,216 B (32 splits)
    float* H    = part + 32 * 512 * 256;                    //    524,288 B
    float* peb  = part;   // alias: read by attn before mlp1 writes part

    hipLaunchKernelGGL(peb_kernel, dim3(640), dim3(256), 0, stream, pe, bp, peb);
    hipLaunchKernelGGL(attn_kernel, dim3(512), dim3(256), 0, stream,
                       lookback, focal, Wp, peb, lng, lnb, flat_hi, flat_lo);
    hipLaunchKernelGGL(mlp1_kernel, dim3(512), dim3(256), 0, stream,
                       flat_hi, flat_lo, W1, part);
    hipLaunchKernelGGL(gelu_kernel, dim3(512), dim3(256), 0, stream, part, b1, H);
    hipLaunchKernelGGL(mlp2_kernel, dim3(32), dim3(256), 0, stream, H, W2, b2,
                       (float*)d_out);
}